// Round 6
// baseline (170.627 us; speedup 1.0000x reference)
//
#include <hip/hip_runtime.h>
#include <cstddef>

#define EPS 1e-5f
static constexpr int Bn = 64, Cn = 64, Hn = 56, Wn = 56, HWn = Hn * Wn; // 3136
static constexpr int CSTR = 136; // ct px stride in shorts: 272 B, 16-B aligned

typedef __attribute__((ext_vector_type(8))) short short8;
typedef __attribute__((ext_vector_type(8))) unsigned short ushort8;
typedef __attribute__((ext_vector_type(4))) float floatx4;
typedef __attribute__((ext_vector_type(16))) float floatx16;
typedef __attribute__((ext_vector_type(4))) unsigned int uintx4;
typedef __attribute__((ext_vector_type(2))) unsigned int uintx2;

__device__ __forceinline__ unsigned pack_rne(float a, float b) {
    unsigned ua = __float_as_uint(a), ub = __float_as_uint(b);
    ua = ua + 0x7fffu + ((ua >> 16) & 1u);
    ub = ub + 0x7fffu + ((ub >> 16) & 1u);
    return __builtin_amdgcn_perm(ub, ua, 0x07060302);
}
__device__ __forceinline__ unsigned pack_trunc(float a, float b) {
    return __builtin_amdgcn_perm(__float_as_uint(b), __float_as_uint(a), 0x07060302);
}
__device__ __forceinline__ ushort8 pmax(ushort8 a, ushort8 b) {
    return __builtin_elementwise_max(a, b);   // valid bf16 max for values >= 0
}
__device__ __forceinline__ float bf_lo(unsigned u) { return __uint_as_float(u << 16); }
__device__ __forceinline__ float bf_hi(unsigned u) { return __uint_as_float(u & 0xffff0000u); }

// node0 layout (bf16): [b][chunk=8][px=3136][j=8]

// ---------------------------------------------------------------------------
// K1: node0 = relu(bn1(conv1x1(x,w1))). bn scale folded into A-frags.
// Direct chunk-split uint2 stores (dense 512-B runs per half-wave).
// ---------------------------------------------------------------------------
__global__ __launch_bounds__(256) void k1_conv1(
    const float* __restrict__ x, const float* __restrict__ w1,
    const float* __restrict__ bg, const float* __restrict__ bb,
    const float* __restrict__ bm, const float* __restrict__ bv,
    unsigned short* __restrict__ node0)
{
    __shared__ float scs[64], shs[64];
    const int tid = threadIdx.x;
    if (tid < 64) {
        float sc = bg[tid] * rsqrtf(bv[tid] + EPS);
        scs[tid] = sc;
        shs[tid] = bb[tid] - bm[tid] * sc;
    }
    __syncthreads();
    const int lane = tid & 63;
    const int wv   = tid >> 6;
    const int m    = lane & 15;
    const int quad = lane >> 4;

    short8 afr[4][2];
    float shv[16];
    #pragma unroll
    for (int t = 0; t < 4; ++t) {
        const float sc = scs[t * 16 + m];
        #pragma unroll
        for (int kk = 0; kk < 2; ++kk) {
            const float* wp = w1 + (t * 16 + m) * 64 + kk * 32 + quad * 8;
            floatx4 f0 = *(const floatx4*)wp;
            floatx4 f1 = *(const floatx4*)(wp + 4);
            uintx4 u;
            u.x = pack_rne(f0[0] * sc, f0[1] * sc);
            u.y = pack_rne(f0[2] * sc, f0[3] * sc);
            u.z = pack_rne(f1[0] * sc, f1[1] * sc);
            u.w = pack_rne(f1[2] * sc, f1[3] * sc);
            afr[t][kk] = *(short8*)&u;
        }
        #pragma unroll
        for (int i = 0; i < 4; ++i) shv[t * 4 + i] = shs[t * 16 + quad * 4 + i];
    }

    #pragma unroll 1
    for (int tt = 0; tt < 4; ++tt) {
        const long P0 = (long)blockIdx.x * 256 + tt * 64;
        const int b = (int)(P0 / HWn);
        const int p0 = (int)(P0 - (long)b * HWn);
        const int p = p0 + wv * 16 + m;

        floatx4 acc[4];
        #pragma unroll
        for (int t = 0; t < 4; ++t) acc[t] = (floatx4){0.f, 0.f, 0.f, 0.f};

        #pragma unroll
        for (int kk = 0; kk < 2; ++kk) {
            float xv[8];
            #pragma unroll
            for (int j = 0; j < 8; ++j)
                xv[j] = x[(size_t)(b * 64 + kk * 32 + quad * 8 + j) * HWn + p];
            uintx4 u;
            u.x = pack_trunc(xv[0], xv[1]);
            u.y = pack_trunc(xv[2], xv[3]);
            u.z = pack_trunc(xv[4], xv[5]);
            u.w = pack_trunc(xv[6], xv[7]);
            short8 bfr = *(short8*)&u;
            #pragma unroll
            for (int t = 0; t < 4; ++t)
                acc[t] = __builtin_amdgcn_mfma_f32_16x16x32_bf16(afr[t][kk], bfr, acc[t], 0, 0, 0);
        }

        const int chunkbase = (quad >> 1);
        const int j0 = (quad & 1) * 4;
        #pragma unroll
        for (int t = 0; t < 4; ++t) {
            float v0 = acc[t][0] + shv[t * 4 + 0]; v0 = v0 > 0.f ? v0 : 0.f;
            float v1 = acc[t][1] + shv[t * 4 + 1]; v1 = v1 > 0.f ? v1 : 0.f;
            float v2 = acc[t][2] + shv[t * 4 + 2]; v2 = v2 > 0.f ? v2 : 0.f;
            float v3 = acc[t][3] + shv[t * 4 + 3]; v3 = v3 > 0.f ? v3 : 0.f;
            uintx2 st;
            st.x = pack_rne(v0, v1);
            st.y = pack_rne(v2, v3);
            int chunk = t * 2 + chunkbase;
            *(uintx2*)(node0 + ((size_t)(b * 8 + chunk) * HWn + p0 + wv * 16 + m) * 8 + j0) = st;
        }
    }
}

// ---------------------------------------------------------------------------
// K23 fused: pools -> LDS cat tile (bf16) -> conv2 32x32 MFMA -> out.
// Block = (b, 4-row band), 512 thr = 8 waves. Phase A: wave = chunk, lane =
// col, packed-u16 pool math, writes ct[224][CSTR]. Phase B: 7 waves x one
// 32-px tile, ds_read_b128 B-frags, w2 staged frag-linear in LDS.
// ---------------------------------------------------------------------------
__global__ __launch_bounds__(512, 4) void k23_fused(
    const unsigned short* __restrict__ node0, const float* __restrict__ w2,
    const float* __restrict__ bg, const float* __restrict__ bb,
    const float* __restrict__ bm, const float* __restrict__ bv,
    float* __restrict__ out)
{
    __shared__ unsigned short ct[224 * CSTR];   // 60928 B cat tile
    __shared__ unsigned short wl[1024 * 8];     // 16 KB frag-linear w2
    __shared__ float scs[64], shs[64];
    const int tid = threadIdx.x;
    if (tid < 64) {
        float sc = bg[tid] * rsqrtf(bv[tid] + EPS);
        scs[tid] = sc;
        shs[tid] = bb[tid] - bm[tid] * sc;
    }
    // stage w2 -> wl: ci = (t*8+kt)*64 + lane', 16 B each
    #pragma unroll
    for (int q = 0; q < 2; ++q) {
        int ci = tid * 2 + q;
        int lane_ = ci & 63, tk = ci >> 6;
        int t = tk >> 3, kt = tk & 7, n_ = lane_ & 31, h_ = lane_ >> 5;
        const float* wp = w2 + (t * 32 + n_) * 128 + kt * 16 + h_ * 8;
        floatx4 f0 = *(const floatx4*)wp;
        floatx4 f1 = *(const floatx4*)(wp + 4);
        uintx4 u;
        u.x = pack_rne(f0[0], f0[1]);
        u.y = pack_rne(f0[2], f0[3]);
        u.z = pack_rne(f1[0], f1[1]);
        u.w = pack_rne(f1[2], f1[3]);
        *(uintx4*)(wl + (size_t)ci * 8) = u;
    }

    const int lane = tid & 63;
    const int wv = tid >> 6;          // phase A: chunk 0..7
    const int b = blockIdx.x / 14;
    const int band = blockIdx.x % 14;
    const int lo = band * 4;
    const int col = lane;
    const bool act = col < Wn;
    const unsigned short* base = node0 + ((size_t)(b * 8 + wv) * HWn) * 8;

    // ---- phase A: pools into ct ----
    {
        const ushort8 zz = (ushort8)0;
        float hs1[8], hs2[8];
        ushort8 h5a = zz, h5b = zz, h5c = zz, h5d = zz, nh1 = zz, nh2 = zz;
        #pragma unroll
        for (int j = 0; j < 8; ++j) hs1[j] = hs2[j] = 0.f;

        #pragma unroll
        for (int r = lo - 2; r <= lo + 5; ++r) {
            ushort8 d[5];
            #pragma unroll
            for (int dd = 0; dd < 5; ++dd) {
                int cc = col + dd - 2;
                bool ok = act && ((unsigned)cc < (unsigned)Wn) && ((unsigned)r < (unsigned)Hn);
                d[dd] = ok ? *(const ushort8*)(base + (size_t)(r * Wn + cc) * 8) : zz;
            }
            ushort8 hm5 = pmax(pmax(pmax(d[0], d[1]), pmax(d[2], d[3])), d[4]);
            ushort8 m5 = pmax(pmax(pmax(h5a, h5b), pmax(h5c, h5d)), hm5);
            h5a = h5b; h5b = h5c; h5c = h5d; h5d = hm5;

            const uintx4 ul = *(const uintx4*)&d[1];
            const uintx4 uv = *(const uintx4*)&d[2];
            const uintx4 ur = *(const uintx4*)&d[3];
            float a2[8];
            const int r2 = r - 1, r3 = r - 2;
            const bool v2 = (unsigned)r2 < (unsigned)Hn;
            #pragma unroll
            for (int w = 0; w < 4; ++w) {
                float hsum0 = bf_lo(ul[w]) + bf_lo(uv[w]) + bf_lo(ur[w]);
                float hsum1 = bf_hi(ul[w]) + bf_hi(uv[w]) + bf_hi(ur[w]);
                a2[w * 2 + 0] = v2 ? (hs2[w * 2 + 0] + hs1[w * 2 + 0] + hsum0) * (1.f / 9.f) : 0.f;
                a2[w * 2 + 1] = v2 ? (hs2[w * 2 + 1] + hs1[w * 2 + 1] + hsum1) * (1.f / 9.f) : 0.f;
                hs2[w * 2 + 0] = hs1[w * 2 + 0]; hs1[w * 2 + 0] = hsum0;
                hs2[w * 2 + 1] = hs1[w * 2 + 1]; hs1[w * 2 + 1] = hsum1;
            }
            uintx4 ap;
            ap.x = pack_rne(a2[0], a2[1]);
            ap.y = pack_rne(a2[2], a2[3]);
            ap.z = pack_rne(a2[4], a2[5]);
            ap.w = pack_rne(a2[6], a2[7]);
            uintx4 al, ar;
            #pragma unroll
            for (int w = 0; w < 4; ++w) {
                unsigned u = ap[w];
                unsigned lu = __shfl_up(u, 1);
                unsigned ru = __shfl_down(u, 1);
                al[w] = (lane == 0) ? 0u : lu;
                ar[w] = (lane == 63) ? 0u : ru;
            }
            ushort8 nh = pmax(pmax(*(ushort8*)&al, *(ushort8*)&ap), *(ushort8*)&ar);
            ushort8 m3 = pmax(pmax(nh2, nh1), nh);
            nh2 = nh1; nh1 = nh;

            if (act && r2 >= lo && r2 < lo + 4) {
                int px = (r2 - lo) * Wn + col;
                *(uintx4*)(ct + (size_t)px * CSTR + wv * 8) = ap;
            }
            if (act && r3 >= lo && r3 < lo + 4) {
                const uintx4 u5 = *(const uintx4*)&m5;
                const uintx4 u3 = *(const uintx4*)&m3;
                uintx4 st;
                #pragma unroll
                for (int w = 0; w < 4; ++w)
                    st[w] = pack_rne(bf_lo(u5[w]) + bf_lo(u3[w]), bf_hi(u5[w]) + bf_hi(u3[w]));
                int px = (r3 - lo) * Wn + col;
                *(uintx4*)(ct + (size_t)px * CSTR + 64 + wv * 8) = st;
            }
        }
    }
    __syncthreads();

    // ---- phase B: conv2 over 7 x 32-px tiles ----
    if (wv >= 7) return;
    const int n = lane & 31;
    const int h = lane >> 5;

    short8 afr[2][8];
    #pragma unroll
    for (int t = 0; t < 2; ++t)
        #pragma unroll
        for (int kt = 0; kt < 8; ++kt)
            afr[t][kt] = *(const short8*)(wl + ((size_t)((t * 8 + kt) * 64 + lane)) * 8);

    const int px0 = wv * 32;
    floatx16 acc0, acc1;
    #pragma unroll
    for (int i = 0; i < 16; ++i) { acc0[i] = 0.f; acc1[i] = 0.f; }

    #pragma unroll
    for (int kt = 0; kt < 8; ++kt) {
        short8 bfr = *(const short8*)(ct + (size_t)(px0 + n) * CSTR + kt * 16 + h * 8);
        acc0 = __builtin_amdgcn_mfma_f32_32x32x16_bf16(afr[0][kt], bfr, acc0, 0, 0, 0);
        acc1 = __builtin_amdgcn_mfma_f32_32x32x16_bf16(afr[1][kt], bfr, acc1, 0, 0, 0);
    }

    float* ob = out + (size_t)b * 64 * HWn + lo * Wn + px0 + n;
    #pragma unroll
    for (int r = 0; r < 16; ++r) {
        int o = (r & 3) + 8 * (r >> 2) + 4 * h;
        float v0 = fmaf(acc0[r], scs[o], shs[o]);
        ob[(size_t)o * HWn] = v0 > 0.f ? v0 : 0.f;
        float v1 = fmaf(acc1[r], scs[o + 32], shs[o + 32]);
        ob[(size_t)(o + 32) * HWn] = v1 > 0.f ? v1 : 0.f;
    }
}

extern "C" void kernel_launch(void* const* d_in, const int* in_sizes, int n_in,
                              void* d_out, int out_size, void* d_ws, size_t ws_size,
                              hipStream_t stream)
{
    const float* x   = (const float*)d_in[0];
    const float* w1  = (const float*)d_in[1];
    const float* w2  = (const float*)d_in[2];
    const float* b1g = (const float*)d_in[3];
    const float* b1b = (const float*)d_in[4];
    const float* b1m = (const float*)d_in[5];
    const float* b1v = (const float*)d_in[6];
    const float* b2g = (const float*)d_in[7];
    const float* b2b = (const float*)d_in[8];
    const float* b2m = (const float*)d_in[9];
    const float* b2v = (const float*)d_in[10];

    float* out = (float*)d_out;
    unsigned short* node0 = (unsigned short*)d_ws;   // 25.7 MB

    k1_conv1<<<dim3(784), dim3(256), 0, stream>>>(x, w1, b1g, b1b, b1m, b1v, node0);
    k23_fused<<<dim3(Bn * 14), dim3(512), 0, stream>>>(node0, w2, b2g, b2b, b2m, b2v, out);
}